// Round 19
// baseline (89.972 us; speedup 1.0000x reference)
//
#include <hip/hip_runtime.h>
#include <hip/hip_bf16.h>

#define NH 32
#define NKVH 8
#define HD 128
#define KT 64
#define QT 32

typedef __attribute__((ext_vector_type(8))) __bf16 bf16x8;
typedef __attribute__((ext_vector_type(4))) __bf16 b16x4;
typedef __attribute__((ext_vector_type(4))) short s16x4;
typedef __attribute__((ext_vector_type(4))) float f32x4;
typedef __attribute__((ext_vector_type(2))) unsigned int u32x2;
typedef __attribute__((ext_vector_type(4))) unsigned int u32x4;

__device__ inline unsigned short f2bf(float f) {
    unsigned int u = __builtin_bit_cast(unsigned int, f);
    u += 0x7fffu + ((u >> 16) & 1u);   // RNE (prep kernel only)
    return (unsigned short)(u >> 16);
}
__device__ inline unsigned int pk2(float lo, float hi) {
    return (unsigned int)f2bf(lo) | ((unsigned int)f2bf(hi) << 16);
}
__device__ inline f32x4 mfma16(bf16x8 a, bf16x8 b, f32x4 c) {
    return __builtin_amdgcn_mfma_f32_16x16x32_bf16(a, b, c, 0, 0, 0);
}
// K=16 MFMA: B-frag layout (col=lane&15, k=lg*4+i) == our S^T D-layout -> zero-shuffle PV
__device__ inline f32x4 mfma16k16(s16x4 a, s16x4 b, f32x4 c) {
#if __has_builtin(__builtin_amdgcn_mfma_f32_16x16x16bf16_1k)
    return __builtin_amdgcn_mfma_f32_16x16x16bf16_1k(a, b, c, 0, 0, 0);
#else
    f32x4 d = c;
    asm volatile("v_mfma_f32_16x16x16_bf16 %0, %1, %2, %0"
                 : "+v"(d) : "v"(a), "v"(b));
    return d;
#endif
}
__device__ inline void async16(unsigned short* lds, const unsigned short* g) {
    __builtin_amdgcn_global_load_lds(
        (const __attribute__((address_space(1))) unsigned int*)g,
        (__attribute__((address_space(3))) unsigned int*)lds, 16, 0, 0);
}
// native-cast pack: compiler emits v_cvt_pk_bf16_f32 (RNE)
__device__ inline s16x4 pack4(f32x4 v) {
    b16x4 h = __builtin_convertvector(v, b16x4);
    return __builtin_bit_cast(s16x4, h);
}
__device__ inline bf16x8 pack8(f32x4 lo, f32x4 hi) {
    struct { s16x4 a, b; } t;
    t.a = pack4(lo);
    t.b = pack4(hi);
    return __builtin_bit_cast(bf16x8, t);
}

// ---- fused prep: K f32 -> bf16 flat, AND V f32 -> bf16 in VT2 layout:
//      VT2[b][kvh][t4][d][4] where t4 = token/4 (so 16B = {d, d+1} x same 4 tokens).
//      Block (0,0,0) also zeroes the work counter.
__global__ __launch_bounds__(256) void prep_kv(const float* __restrict__ kg,
                                               const float* __restrict__ vg,
                                               const int* __restrict__ cu,
                                               unsigned short* __restrict__ kb,
                                               unsigned short* __restrict__ vt,
                                               int* __restrict__ ctr) {
    const int b = blockIdx.y, kvh = blockIdx.z;
    if (blockIdx.x == 0 && b == 0 && kvh == 0 && threadIdx.x == 0) *ctr = 0;
    const int bstart = cu[b];
    const int L = cu[b + 1] - bstart;
    const int kv0 = blockIdx.x * 64;
    if (kv0 >= L) return;
    const int tid = threadIdx.x;
    const int wid = tid >> 6, lane = tid & 63;
    __shared__ __align__(16) unsigned short Vl[HD * 64];

    // V: load rows, transpose into LDS (swizzled pairs)
    #pragma unroll
    for (int it = 0; it < 4; ++it) {
        int jp = wid * 8 + (lane >> 3);
        int c4 = (lane & 7) + it * 8;
        int j0 = jp * 2;
        int jj0 = kv0 + j0;
        f32x4 va = f32x4{0.f, 0.f, 0.f, 0.f}, vb = f32x4{0.f, 0.f, 0.f, 0.f};
        if (jj0 < L)     va = *(const f32x4*)&vg[(size_t)(bstart + jj0) * (NKVH * HD) + kvh * HD + c4 * 4];
        if (jj0 + 1 < L) vb = *(const f32x4*)&vg[(size_t)(bstart + jj0 + 1) * (NKVH * HD) + kvh * HD + c4 * 4];
        #pragma unroll
        for (int i = 0; i < 4; ++i) {
            int d = c4 * 4 + i;
            int idx = (d * 64 + j0) ^ ((d & 7) << 3);
            *(unsigned int*)&Vl[idx] = pk2(va[i], vb[i]);
        }
    }

    // K: convert this (b, kvh, 64-token) slice, same flat layout
    #pragma unroll
    for (int it = 0; it < 4; ++it) {
        int u = tid + it * 256;          // 1024 units of 8 elems
        int j = u >> 4, c8 = u & 15;
        int jj = kv0 + j;
        if (jj < L) {
            const float* p = &kg[(size_t)(bstart + jj) * (NKVH * HD) + kvh * HD + c8 * 8];
            f32x4 a = *(const f32x4*)p;
            f32x4 bq = *(const f32x4*)(p + 4);
            u32x4 r = {pk2(a[0], a[1]), pk2(a[2], a[3]), pk2(bq[0], bq[1]), pk2(bq[2], bq[3])};
            *(u32x4*)&kb[(size_t)(bstart + jj) * (NKVH * HD) + kvh * HD + c8 * 8] = r;
        }
    }
    __syncthreads();

    // VT2 write-out: piece (t4l, d) = V^T[d][t4l*4 .. +3] (8B), d-major for coalescing
    const size_t vtb = (size_t)bstart * (NKVH * HD) + (size_t)kvh * HD * L;
    #pragma unroll
    for (int it = 0; it < 8; ++it) {
        int u = tid + it * 256;          // 2048 pieces
        int d = u & 127, t4l = u >> 7;
        int j0 = t4l * 4;
        if (kv0 + j0 >= L) continue;
        int idx = d * 64 + (j0 ^ ((d & 7) << 3));
        u32x2 w = *(const u32x2*)&Vl[idx];
        *(u32x2*)&vt[vtb + ((size_t)((kv0 >> 2) + t4l) * HD + d) * 4] = w;
    }
}

// ---- persistent fused attention (fa16 schedule; READ-ORDER-LINEAR LDS):
// K and V LDS tiles are laid out in exactly the order the MFMA fragments read
// them: slot ((s*4+kk)*64+lane)*16B for K, ((s*8+dsb)*64+lane)*8B for V. Every
// ds_read is base + lane*width + imm offset -> conflict-free, zero addr VALU.
// Stage side inverts the permutation via per-lane global source addressing.
// Swapped QK; no-max softmax; zero-shuffle K=16 PV; rt-hoisted fragment reuse.
__global__ __launch_bounds__(256, 2) void fa19(const float* __restrict__ qg,
                                               const unsigned short* __restrict__ kb,
                                               const unsigned short* __restrict__ vt,
                                               const int* __restrict__ cu,
                                               float* __restrict__ outg,
                                               int* __restrict__ ctr, int B) {
    const int tid = threadIdx.x;
    const int wid = tid >> 6, lane = tid & 63;
    const int lg = lane >> 4, lr = lane & 15;

    __shared__ __align__(16) unsigned short Klds[2][KT * HD];   // 2 x 16 KB (1024 slots x 16B)
    __shared__ __align__(16) unsigned short Vlds[2][HD * KT];   // 2 x 16 KB (2048 slots x 8B)
    __shared__ int s_item;

    // total q-tile count across batches (uniform scalar)
    int totalF = 0;
    {
        int prev = cu[0];
        #pragma unroll 1
        for (int bb = 0; bb < B; ++bb) {
            int nxt = cu[bb + 1];
            totalF += (nxt - prev + QT - 1) / QT;
            prev = nxt;
        }
    }
    const int totalItems = totalF * NKVH;
    const float scv = 0.08838834764831843f * 1.4426950408889634f; // 1/sqrt(128)*log2(e)

    for (;;) {
        if (tid == 0) s_item = atomicAdd(ctr, 1);
        __syncthreads();
        const int item = s_item;
        if (item >= totalItems) return;

        // item -> (kvh, f): same-kvh items adjacent (L2 K/V sharing)
        const int kvh = item / totalF;
        const int f = item - kvh * totalF;
        // f -> (batch, qt) heavy-first within batch (scalar, no local arrays)
        int rem = f, bstart = 0, L = 0, nqf = 0, found = 0;
        int prev = cu[0];
        #pragma unroll 1
        for (int bb = 0; bb < B; ++bb) {
            int nxt = cu[bb + 1];
            int len = nxt - prev;
            int nq = (len + QT - 1) / QT;
            if (!found) {
                if (rem < nq) { bstart = prev; L = len; nqf = nq; found = 1; }
                else rem -= nq;
            }
            prev = nxt;
        }
        const int qt = nqf - 1 - rem;     // heavy-first
        const int q0 = qt * QT;
        const int h = kvh * 4 + wid;

        // ---- Q fragments, pre-scaled (B-frag for QK: col=lr, k=lg*8+i per 32-slice)
        bf16x8 qf0[4], qf1[4];
        #pragma unroll
        for (int kk = 0; kk < 4; ++kk) {
            int row0 = q0 + lr;
            int tok0 = bstart + (row0 < L ? row0 : L - 1);
            const float* p = &qg[(size_t)tok0 * (NH * HD) + h * HD + kk * 32 + lg * 8];
            f32x4 a = *(const f32x4*)p;
            f32x4 bq = *(const f32x4*)(p + 4);
            qf0[kk] = pack8(a * scv, bq * scv);
        }
        #pragma unroll
        for (int kk = 0; kk < 4; ++kk) {
            int row1 = q0 + 16 + lr;
            int tok1 = bstart + (row1 < L ? row1 : L - 1);
            const float* p = &qg[(size_t)tok1 * (NH * HD) + h * HD + kk * 32 + lg * 8];
            f32x4 a = *(const f32x4*)p;
            f32x4 bq = *(const f32x4*)(p + 4);
            qf1[kk] = pack8(a * scv, bq * scv);
        }

        f32x4 acc0[8], acc1[8];
        #pragma unroll
        for (int i = 0; i < 8; ++i) {
            acc0[i] = f32x4{0.f, 0.f, 0.f, 0.f};
            acc1[i] = f32x4{0.f, 0.f, 0.f, 0.f};
        }
        float lsum0 = 0.f, lsum1 = 0.f;

        const int ntiles = (q0 + QT + KT - 1) / KT;
        const unsigned short* kbase = kb + (size_t)bstart * (NKVH * HD) + kvh * HD;
        const unsigned short* vbase = vt + (size_t)bstart * (NKVH * HD) + (size_t)kvh * HD * L;
        const int t4m = (L >> 2) - 1;

        auto STAGE = [&](int buf, int kv0) {
            unsigned short* Kd = Klds[buf];
            unsigned short* Vd = Vlds[buf];
            // K: slot sl (16B) = inst (s*4+kk) x lane lam: row kv0+s*16+(lam&15),
            //    cols kk*32 + (lam>>4)*8 .. +7  (contiguous 16B in flat kb)
            #pragma unroll
            for (int i = 0; i < 4; ++i) {
                int sl = i * 256 + tid;
                int inst = sl >> 6, lam = sl & 63;
                int s = inst >> 2, kk = inst & 3;
                int jj = kv0 + s * 16 + (lam & 15);
                if (jj >= L) jj = L - 1;
                async16(Kd + (size_t)sl * 8,
                        kbase + (size_t)jj * (NKVH * HD) + kk * 32 + (lam >> 4) * 8);
            }
            // V: stage unit sl (16B) = slots {2m, 2m+1} of inst (s*8+dsb):
            //    d0 = dsb*16 + 2*(m&7), token-block t4 = kv0/4 + s*4 + (m>>3)
            //    VT2 gives {d0, d0+1} x same 4 tokens as contiguous 16B.
            #pragma unroll
            for (int i = 0; i < 4; ++i) {
                int sl = i * 256 + tid;
                int inst = sl >> 5, m = sl & 31;
                int s = inst >> 3, dsb = inst & 7;
                int d0 = dsb * 16 + 2 * (m & 7);
                int t4 = (kv0 >> 2) + s * 4 + (m >> 3);
                if (t4 > t4m) t4 = t4m;
                async16(Vd + (size_t)sl * 8, vbase + ((size_t)t4 * HD + d0) * 4);
            }
        };

        STAGE(0, 0);
        __syncthreads();

        for (int kt = 0; kt < ntiles; ++kt) {
            const int kv0 = kt * KT;
            const int buf = kt & 1;
            if (kt + 1 < ntiles) STAGE(buf ^ 1, kv0 + KT);   // prefetch overlaps compute

            const unsigned short* Kc = Klds[buf];
            const unsigned short* Vc = Vlds[buf];

            const int shi_raw = ((q0 + QT - 1 - kv0) >> 4) + 1;
            const int s_hi = shi_raw < 4 ? shi_raw : 4;
            const bool needmask = (kv0 + KT - 1) > q0;
            const int qpos0 = q0 + lr;          // rt=0 lane's q-row
            const int qpos1 = q0 + 16 + lr;     // rt=1 lane's q-row

            // ---- S^T = K Q^T, both rt share each kf read (linear LDS: lane*16 + imm)
            f32x4 st0[4], st1[4];
            __builtin_amdgcn_s_setprio(1);
            #pragma unroll
            for (int s = 0; s < 4; ++s) {
                if (s < s_hi) {
                    f32x4 a0 = f32x4{0.f, 0.f, 0.f, 0.f};
                    f32x4 a1 = f32x4{0.f, 0.f, 0.f, 0.f};
                    #pragma unroll
                    for (int kk = 0; kk < 4; ++kk) {
                        bf16x8 kf = *(const bf16x8*)&Kc[(((s * 4 + kk) * 64) + lane) * 8];
                        a0 = mfma16(kf, qf0[kk], a0);
                        a1 = mfma16(kf, qf1[kk], a1);
                    }
                    st0[s] = a0;
                    st1[s] = a1;
                }
            }
            __builtin_amdgcn_s_setprio(0);

            // ---- P = exp2(S) (no max; shift-invariant), mask via select-zero
            #pragma unroll
            for (int s = 0; s < 4; ++s) {
                if (s < s_hi) {
                    #pragma unroll
                    for (int r = 0; r < 4; ++r) {
                        int j = kv0 + s * 16 + lg * 4 + r;
                        float p0 = __builtin_amdgcn_exp2f(st0[s][r]);
                        float p1 = __builtin_amdgcn_exp2f(st1[s][r]);
                        p0 = (needmask && j > qpos0) ? 0.f : p0;
                        p1 = (needmask && j > qpos1) ? 0.f : p1;
                        st0[s][r] = p0;
                        st1[s][r] = p1;
                        lsum0 += p0;
                        lsum1 += p1;
                    }
                }
            }

            // ---- PV: packed P IS the K=16 B-frag; linear LDS V (lane*8 + imm)
            #pragma unroll
            for (int s = 0; s < 4; ++s) {
                if (s < s_hi) {
                    s16x4 pb0 = pack4(st0[s]);
                    s16x4 pb1 = pack4(st1[s]);
                    __builtin_amdgcn_s_setprio(1);
                    #pragma unroll
                    for (int dsb = 0; dsb < 8; ++dsb) {
                        s16x4 vf = *(const s16x4*)&Vc[(((s * 8 + dsb) * 64) + lane) * 4];
                        acc0[dsb] = mfma16k16(vf, pb0, acc0[dsb]);
                        acc1[dsb] = mfma16k16(vf, pb1, acc1[dsb]);
                    }
                    __builtin_amdgcn_s_setprio(0);
                }
            }
            __syncthreads();   // all waves done with cur buffers; prefetch drained
        }

        // ---- epilogue: reduce l across k-groups (once), O^T -> O, f32x4 stores
        {
            float l = lsum0;
            l += __shfl_xor(l, 16);
            l += __shfl_xor(l, 32);
            int q = q0 + lr;
            if (q < L) {
                float inv = 1.0f / l;
                size_t base = (size_t)(bstart + q) * (NH * HD) + h * HD;
                #pragma unroll
                for (int dsb = 0; dsb < 8; ++dsb) {
                    f32x4 o = acc0[dsb] * inv;
                    *(f32x4*)&outg[base + dsb * 16 + lg * 4] = o;
                }
            }
        }
        {
            float l = lsum1;
            l += __shfl_xor(l, 16);
            l += __shfl_xor(l, 32);
            int q = q0 + 16 + lr;
            if (q < L) {
                float inv = 1.0f / l;
                size_t base = (size_t)(bstart + q) * (NH * HD) + h * HD;
                #pragma unroll
                for (int dsb = 0; dsb < 8; ++dsb) {
                    f32x4 o = acc1[dsb] * inv;
                    *(f32x4*)&outg[base + dsb * 16 + lg * 4] = o;
                }
            }
        }
    }
}

extern "C" void kernel_launch(void* const* d_in, const int* in_sizes, int n_in,
                              void* d_out, int out_size, void* d_ws, size_t ws_size,
                              hipStream_t stream) {
    const float* q = (const float*)d_in[0];
    const float* k = (const float*)d_in[1];
    const float* v = (const float*)d_in[2];
    const int* cu  = (const int*)d_in[3];
    int T = in_sizes[0] / (NH * HD);
    int B = in_sizes[3] - 1;

    // workspace: Kb [T*1024] bf16, VT2 [T*1024] bf16, then work counter (13.1 MB + 4 B)
    unsigned short* kb = (unsigned short*)d_ws;
    unsigned short* vt = kb + (size_t)T * (NKVH * HD);
    int* ctr = (int*)(vt + (size_t)T * (NKVH * HD));

    dim3 gkv((T + 63) / 64, B, NKVH);
    prep_kv<<<gkv, 256, 0, stream>>>(k, v, cu, kb, vt, ctr);

    fa19<<<dim3(512), dim3(256), 0, stream>>>(q, kb, vt, cu, (float*)d_out, ctr, B);
}

// Round 20
// 83.765 us; speedup vs baseline: 1.0741x; 1.0741x over previous
//
#include <hip/hip_runtime.h>
#include <hip/hip_bf16.h>

#define NH 32
#define NKVH 8
#define HD 128
#define KT 64
#define QT 32

typedef __attribute__((ext_vector_type(8))) __bf16 bf16x8;
typedef __attribute__((ext_vector_type(4))) __bf16 b16x4;
typedef __attribute__((ext_vector_type(4))) short s16x4;
typedef __attribute__((ext_vector_type(4))) float f32x4;
typedef __attribute__((ext_vector_type(2))) unsigned int u32x2;
typedef __attribute__((ext_vector_type(4))) unsigned int u32x4;

__device__ inline unsigned short f2bf(float f) {
    unsigned int u = __builtin_bit_cast(unsigned int, f);
    u += 0x7fffu + ((u >> 16) & 1u);   // RNE (prep kernel only)
    return (unsigned short)(u >> 16);
}
__device__ inline unsigned int pk2(float lo, float hi) {
    return (unsigned int)f2bf(lo) | ((unsigned int)f2bf(hi) << 16);
}
__device__ inline f32x4 mfma16(bf16x8 a, bf16x8 b, f32x4 c) {
    return __builtin_amdgcn_mfma_f32_16x16x32_bf16(a, b, c, 0, 0, 0);
}
// K=16 MFMA: B-frag layout (col=lane&15, k=lg*4+i) == our S^T D-layout -> zero-shuffle PV
__device__ inline f32x4 mfma16k16(s16x4 a, s16x4 b, f32x4 c) {
#if __has_builtin(__builtin_amdgcn_mfma_f32_16x16x16bf16_1k)
    return __builtin_amdgcn_mfma_f32_16x16x16bf16_1k(a, b, c, 0, 0, 0);
#else
    f32x4 d = c;
    asm volatile("v_mfma_f32_16x16x16_bf16 %0, %1, %2, %0"
                 : "+v"(d) : "v"(a), "v"(b));
    return d;
#endif
}
__device__ inline void async16(unsigned short* lds, const unsigned short* g) {
    __builtin_amdgcn_global_load_lds(
        (const __attribute__((address_space(1))) unsigned int*)g,
        (__attribute__((address_space(3))) unsigned int*)lds, 16, 0, 0);
}
// native-cast pack: compiler emits v_cvt_pk_bf16_f32 (RNE)
__device__ inline s16x4 pack4(f32x4 v) {
    b16x4 h = __builtin_convertvector(v, b16x4);
    return __builtin_bit_cast(s16x4, h);
}
__device__ inline bf16x8 pack8(f32x4 lo, f32x4 hi) {
    struct { s16x4 a, b; } t;
    t.a = pack4(lo);
    t.b = pack4(hi);
    return __builtin_bit_cast(bf16x8, t);
}

// ---- fused prep into FRAGMENT-SLOT-ORDERED tiles (per (b,kvh,64-token tile)):
//  kb2: 1024 x 16B slots; slot sl = (s*4+kk)*64 + lam holds
//       K[kv0+s*16+(lam&15)][kk*32+(lam>>4)*8 .. +7]
//  vt3: 2048 x 8B slots; slot vsl = (s*8+dsb)*64 + lg*16 + lr holds
//       V^T[dsb*16+lr][kv0+s*16+lg*4 .. +3]
// Attention STAGE becomes a pure linear copy. Block (0,0,0) zeroes the counter.
__global__ __launch_bounds__(256) void prep_kv(const float* __restrict__ kg,
                                               const float* __restrict__ vg,
                                               const int* __restrict__ cu,
                                               unsigned short* __restrict__ kb,
                                               unsigned short* __restrict__ vt,
                                               int* __restrict__ ctr) {
    const int b = blockIdx.y, kvh = blockIdx.z;
    if (blockIdx.x == 0 && b == 0 && kvh == 0 && threadIdx.x == 0) *ctr = 0;
    const int bstart = cu[b];
    const int L = cu[b + 1] - bstart;
    const int kv0 = blockIdx.x * 64;
    if (kv0 >= L) return;
    const int tid = threadIdx.x;
    const int wid = tid >> 6, lane = tid & 63;
    __shared__ __align__(16) unsigned short Vl[HD * 64];

    const size_t ktile = (size_t)bstart * (NKVH * HD) + (size_t)kvh * HD * L
                       + (size_t)(kv0 >> 6) * 8192;   // per-tile 8192 halfs = 16KB

    // V: load rows, transpose into LDS (swizzled pairs)
    #pragma unroll
    for (int it = 0; it < 4; ++it) {
        int jp = wid * 8 + (lane >> 3);
        int c4 = (lane & 7) + it * 8;
        int j0 = jp * 2;
        int jj0 = kv0 + j0;
        f32x4 va = f32x4{0.f, 0.f, 0.f, 0.f}, vb = f32x4{0.f, 0.f, 0.f, 0.f};
        if (jj0 < L)     va = *(const f32x4*)&vg[(size_t)(bstart + jj0) * (NKVH * HD) + kvh * HD + c4 * 4];
        if (jj0 + 1 < L) vb = *(const f32x4*)&vg[(size_t)(bstart + jj0 + 1) * (NKVH * HD) + kvh * HD + c4 * 4];
        #pragma unroll
        for (int i = 0; i < 4; ++i) {
            int d = c4 * 4 + i;
            int idx = (d * 64 + j0) ^ ((d & 7) << 3);
            *(unsigned int*)&Vl[idx] = pk2(va[i], vb[i]);
        }
    }

    // K: read rows coalesced, write fragment-slot-ordered 16B units
    #pragma unroll
    for (int it = 0; it < 4; ++it) {
        int u = tid + it * 256;          // 1024 units
        int j = u >> 4, c8 = u & 15;     // row-in-tile, col-oct
        int jj = kv0 + j;
        if (jj < L) {
            const float* p = &kg[(size_t)(bstart + jj) * (NKVH * HD) + kvh * HD + c8 * 8];
            f32x4 a = *(const f32x4*)p;
            f32x4 bq = *(const f32x4*)(p + 4);
            u32x4 r = {pk2(a[0], a[1]), pk2(a[2], a[3]), pk2(bq[0], bq[1]), pk2(bq[2], bq[3])};
            int sl = ((j >> 4) * 4 + (c8 >> 2)) * 64 + (c8 & 3) * 16 + (j & 15);
            *(u32x4*)&kb[ktile + (size_t)sl * 8] = r;
        }
    }
    __syncthreads();

    // V write-out: piece (t4l, d) -> slot vsl, contiguous for consecutive d
    const size_t vtile = (size_t)bstart * (NKVH * HD) + (size_t)kvh * HD * L
                       + (size_t)(kv0 >> 6) * 8192;
    #pragma unroll
    for (int it = 0; it < 8; ++it) {
        int u = tid + it * 256;          // 2048 pieces of 8B
        int d = u & 127, t4l = u >> 7;
        int j0 = t4l * 4;
        if (kv0 + j0 >= L) continue;
        int idx = d * 64 + (j0 ^ ((d & 7) << 3));
        u32x2 w = *(const u32x2*)&Vl[idx];
        int vsl = ((t4l >> 2) * 8 + (d >> 4)) * 64 + (t4l & 3) * 16 + (d & 15);
        *(u32x2*)&vt[vtile + (size_t)vsl * 4] = w;
    }
}

// ---- persistent fused attention (fa19 read path; LINEAR staging):
// K/V global buffers are fragment-slot-ordered per tile, so STAGE is a pure
// linear copy (zero addr VALU, perfectly coalesced) and every ds_read is
// base + lane*width + imm (zero bank conflicts). Swapped QK; no-max softmax;
// zero-shuffle K=16 PV; rt-hoisted fragment reuse; cvt_pk packing.
__global__ __launch_bounds__(256, 2) void fa20(const float* __restrict__ qg,
                                               const unsigned short* __restrict__ kb,
                                               const unsigned short* __restrict__ vt,
                                               const int* __restrict__ cu,
                                               float* __restrict__ outg,
                                               int* __restrict__ ctr, int B) {
    const int tid = threadIdx.x;
    const int wid = tid >> 6, lane = tid & 63;
    const int lg = lane >> 4, lr = lane & 15;

    __shared__ __align__(16) unsigned short Klds[2][KT * HD];   // 2 x 16 KB
    __shared__ __align__(16) unsigned short Vlds[2][HD * KT];   // 2 x 16 KB
    __shared__ int s_item;

    // total q-tile count across batches (uniform scalar)
    int totalF = 0;
    {
        int prev = cu[0];
        #pragma unroll 1
        for (int bb = 0; bb < B; ++bb) {
            int nxt = cu[bb + 1];
            totalF += (nxt - prev + QT - 1) / QT;
            prev = nxt;
        }
    }
    const int totalItems = totalF * NKVH;
    const float scv = 0.08838834764831843f * 1.4426950408889634f; // 1/sqrt(128)*log2(e)

    for (;;) {
        if (tid == 0) s_item = atomicAdd(ctr, 1);
        __syncthreads();
        const int item = s_item;
        if (item >= totalItems) return;

        // item -> (kvh, f): same-kvh items adjacent (L2 K/V sharing)
        const int kvh = item / totalF;
        const int f = item - kvh * totalF;
        // f -> (batch, qt) heavy-first within batch (scalar, no local arrays)
        int rem = f, bstart = 0, L = 0, nqf = 0, found = 0;
        int prev = cu[0];
        #pragma unroll 1
        for (int bb = 0; bb < B; ++bb) {
            int nxt = cu[bb + 1];
            int len = nxt - prev;
            int nq = (len + QT - 1) / QT;
            if (!found) {
                if (rem < nq) { bstart = prev; L = len; nqf = nq; found = 1; }
                else rem -= nq;
            }
            prev = nxt;
        }
        const int qt = nqf - 1 - rem;     // heavy-first
        const int q0 = qt * QT;
        const int h = kvh * 4 + wid;

        // ---- Q fragments, pre-scaled (B-frag for QK: col=lr, k=lg*8+i per 32-slice)
        bf16x8 qf0[4], qf1[4];
        #pragma unroll
        for (int kk = 0; kk < 4; ++kk) {
            int row0 = q0 + lr;
            int tok0 = bstart + (row0 < L ? row0 : L - 1);
            const float* p = &qg[(size_t)tok0 * (NH * HD) + h * HD + kk * 32 + lg * 8];
            f32x4 a = *(const f32x4*)p;
            f32x4 bq = *(const f32x4*)(p + 4);
            qf0[kk] = pack8(a * scv, bq * scv);
        }
        #pragma unroll
        for (int kk = 0; kk < 4; ++kk) {
            int row1 = q0 + 16 + lr;
            int tok1 = bstart + (row1 < L ? row1 : L - 1);
            const float* p = &qg[(size_t)tok1 * (NH * HD) + h * HD + kk * 32 + lg * 8];
            f32x4 a = *(const f32x4*)p;
            f32x4 bq = *(const f32x4*)(p + 4);
            qf1[kk] = pack8(a * scv, bq * scv);
        }

        f32x4 acc0[8], acc1[8];
        #pragma unroll
        for (int i = 0; i < 8; ++i) {
            acc0[i] = f32x4{0.f, 0.f, 0.f, 0.f};
            acc1[i] = f32x4{0.f, 0.f, 0.f, 0.f};
        }
        float lsum0 = 0.f, lsum1 = 0.f;

        const int ntiles = (q0 + QT + KT - 1) / KT;
        const unsigned short* kbase = kb + (size_t)bstart * (NKVH * HD) + (size_t)kvh * HD * L;
        const unsigned short* vbase = vt + (size_t)bstart * (NKVH * HD) + (size_t)kvh * HD * L;

        auto STAGE = [&](int buf, int kv0) {
            unsigned short* Kd = Klds[buf];
            unsigned short* Vd = Vlds[buf];
            const unsigned short* k2 = kbase + (size_t)(kv0 >> 6) * 8192;
            const unsigned short* v3 = vbase + (size_t)(kv0 >> 6) * 8192;
            #pragma unroll
            for (int i = 0; i < 4; ++i) {                 // K: 1024 16B units, linear
                int U = i * 256 + tid;
                async16(Kd + (size_t)U * 8, k2 + (size_t)U * 8);
            }
            #pragma unroll
            for (int i = 0; i < 4; ++i) {                 // V: 1024 16B units, linear
                int U = i * 256 + tid;
                async16(Vd + (size_t)U * 8, v3 + (size_t)U * 8);
            }
        };

        STAGE(0, 0);
        __syncthreads();

        for (int kt = 0; kt < ntiles; ++kt) {
            const int kv0 = kt * KT;
            const int buf = kt & 1;
            if (kt + 1 < ntiles) STAGE(buf ^ 1, kv0 + KT);   // prefetch overlaps compute

            const unsigned short* Kc = Klds[buf];
            const unsigned short* Vc = Vlds[buf];

            const int shi_raw = ((q0 + QT - 1 - kv0) >> 4) + 1;
            const int s_hi = shi_raw < 4 ? shi_raw : 4;
            const bool needmask = (kv0 + KT - 1) > q0;
            const int qpos0 = q0 + lr;          // rt=0 lane's q-row
            const int qpos1 = q0 + 16 + lr;     // rt=1 lane's q-row

            // ---- S^T = K Q^T, both rt share each kf read (linear LDS: lane*16 + imm)
            f32x4 st0[4], st1[4];
            __builtin_amdgcn_s_setprio(1);
            #pragma unroll
            for (int s = 0; s < 4; ++s) {
                if (s < s_hi) {
                    f32x4 a0 = f32x4{0.f, 0.f, 0.f, 0.f};
                    f32x4 a1 = f32x4{0.f, 0.f, 0.f, 0.f};
                    #pragma unroll
                    for (int kk = 0; kk < 4; ++kk) {
                        bf16x8 kf = *(const bf16x8*)&Kc[(((s * 4 + kk) * 64) + lane) * 8];
                        a0 = mfma16(kf, qf0[kk], a0);
                        a1 = mfma16(kf, qf1[kk], a1);
                    }
                    st0[s] = a0;
                    st1[s] = a1;
                }
            }
            __builtin_amdgcn_s_setprio(0);

            // ---- P = exp2(S) (no max; shift-invariant), mask via select-zero
            #pragma unroll
            for (int s = 0; s < 4; ++s) {
                if (s < s_hi) {
                    #pragma unroll
                    for (int r = 0; r < 4; ++r) {
                        int j = kv0 + s * 16 + lg * 4 + r;
                        float p0 = __builtin_amdgcn_exp2f(st0[s][r]);
                        float p1 = __builtin_amdgcn_exp2f(st1[s][r]);
                        p0 = (needmask && j > qpos0) ? 0.f : p0;
                        p1 = (needmask && j > qpos1) ? 0.f : p1;
                        st0[s][r] = p0;
                        st1[s][r] = p1;
                        lsum0 += p0;
                        lsum1 += p1;
                    }
                }
            }

            // ---- PV: packed P IS the K=16 B-frag; linear LDS V (lane*8 + imm)
            #pragma unroll
            for (int s = 0; s < 4; ++s) {
                if (s < s_hi) {
                    s16x4 pb0 = pack4(st0[s]);
                    s16x4 pb1 = pack4(st1[s]);
                    __builtin_amdgcn_s_setprio(1);
                    #pragma unroll
                    for (int dsb = 0; dsb < 8; ++dsb) {
                        s16x4 vf = *(const s16x4*)&Vc[(((s * 8 + dsb) * 64) + lane) * 4];
                        acc0[dsb] = mfma16k16(vf, pb0, acc0[dsb]);
                        acc1[dsb] = mfma16k16(vf, pb1, acc1[dsb]);
                    }
                    __builtin_amdgcn_s_setprio(0);
                }
            }
            __syncthreads();   // all waves done with cur buffers; prefetch drained
        }

        // ---- epilogue: reduce l across k-groups (once), O^T -> O, f32x4 stores
        {
            float l = lsum0;
            l += __shfl_xor(l, 16);
            l += __shfl_xor(l, 32);
            int q = q0 + lr;
            if (q < L) {
                float inv = 1.0f / l;
                size_t base = (size_t)(bstart + q) * (NH * HD) + h * HD;
                #pragma unroll
                for (int dsb = 0; dsb < 8; ++dsb) {
                    f32x4 o = acc0[dsb] * inv;
                    *(f32x4*)&outg[base + dsb * 16 + lg * 4] = o;
                }
            }
        }
        {
            float l = lsum1;
            l += __shfl_xor(l, 16);
            l += __shfl_xor(l, 32);
            int q = q0 + 16 + lr;
            if (q < L) {
                float inv = 1.0f / l;
                size_t base = (size_t)(bstart + q) * (NH * HD) + h * HD;
                #pragma unroll
                for (int dsb = 0; dsb < 8; ++dsb) {
                    f32x4 o = acc1[dsb] * inv;
                    *(f32x4*)&outg[base + dsb * 16 + lg * 4] = o;
                }
            }
        }
    }
}

extern "C" void kernel_launch(void* const* d_in, const int* in_sizes, int n_in,
                              void* d_out, int out_size, void* d_ws, size_t ws_size,
                              hipStream_t stream) {
    const float* q = (const float*)d_in[0];
    const float* k = (const float*)d_in[1];
    const float* v = (const float*)d_in[2];
    const int* cu  = (const int*)d_in[3];
    int T = in_sizes[0] / (NH * HD);
    int B = in_sizes[3] - 1;

    // workspace: Kb2 [T*1024] bf16, VT3 [T*1024] bf16, then work counter (13.1 MB + 4 B)
    unsigned short* kb = (unsigned short*)d_ws;
    unsigned short* vt = kb + (size_t)T * (NKVH * HD);
    int* ctr = (int*)(vt + (size_t)T * (NKVH * HD));

    dim3 gkv((T + 63) / 64, B, NKVH);
    prep_kv<<<gkv, 256, 0, stream>>>(k, v, cu, kb, vt, ctr);

    fa20<<<dim3(512), dim3(256), 0, stream>>>(q, kb, vt, cu, (float*)d_out, ctr, B);
}